// Round 3
// baseline (333.330 us; speedup 1.0000x reference)
//
#include <hip/hip_runtime.h>

// EfConv forward, CSR-based (no fp32 atomics):
//   1. t = node_feat @ W^T  [N,64]  (+ zero deg, fused)
//   2. deg[d] = #edges with dst==d        (int atomics, int4 loads)
//   3. offsets = exclusive_scan(deg)      (3-kernel scan, tiny)
//   4. permute: pos=cursor[dst[e]]++; src_s[pos]=src[e]; ef_s[pos]=ef[e]
//      (ef permuted here so the aggregate reads it STREAMING; falls back to a
//       perm[] indirection if ws_size is too small for ef_s)
//   5. aggregate: per node (one wave, lanes=o), 4-edge unrolled,
//      NON-TEMPORAL output stores (write-once data must not evict t/ef from LLC)

#define FEATS 64
#define EDGE_DIM 8

// ---- Kernel 1: t[n][o] = sum_i nf[n][i] * W[o][i]; also zeroes deg ----
__global__ void __launch_bounds__(256) transform_kernel(
    const float* __restrict__ nf, const float* __restrict__ W,
    float* __restrict__ t, int* __restrict__ deg, int n_nodes)
{
    __shared__ float sWt[FEATS * 65];
    __shared__ float srow[4][FEATS];
    const int tid = threadIdx.x;

    #pragma unroll
    for (int base = 0; base < FEATS * FEATS; base += 256) {
        int idx = base + tid;
        sWt[(idx & 63) * 65 + (idx >> 6)] = W[idx];
    }

    const int r = tid >> 6;
    const int o = tid & 63;
    const int node = blockIdx.x * 4 + r;
    if (node < n_nodes) srow[r][o] = nf[(long)node * FEATS + o];
    if (tid < 4) {
        int zn = blockIdx.x * 4 + tid;
        if (zn < n_nodes) deg[zn] = 0;
    }
    __syncthreads();

    if (node >= n_nodes) return;
    float sum = 0.f;
    #pragma unroll
    for (int i = 0; i < FEATS; i++)
        sum += srow[r][i] * sWt[i * 65 + o];
    t[(long)node * FEATS + o] = sum;
}

// ---- Kernel 2: histogram of dst, 4 edges/thread ----
__global__ void __launch_bounds__(256) hist_kernel(
    const int* __restrict__ dst, int* __restrict__ deg, int n_edges)
{
    int i = (blockIdx.x * 256 + threadIdx.x) * 4;
    if (i + 3 < n_edges) {
        int4 d = *(const int4*)(dst + i);
        atomicAdd(&deg[d.x], 1);
        atomicAdd(&deg[d.y], 1);
        atomicAdd(&deg[d.z], 1);
        atomicAdd(&deg[d.w], 1);
    } else {
        for (int e = i; e < n_edges; e++) atomicAdd(&deg[dst[e]], 1);
    }
}

// ---- Kernel 3a: per-block partial sums of deg ----
__global__ void __launch_bounds__(256) partials_kernel(
    const int* __restrict__ deg, int* __restrict__ partials, int n)
{
    __shared__ int s[256];
    int i = blockIdx.x * 256 + threadIdx.x;
    s[threadIdx.x] = (i < n) ? deg[i] : 0;
    __syncthreads();
    for (int off = 128; off > 0; off >>= 1) {
        if (threadIdx.x < off) s[threadIdx.x] += s[threadIdx.x + off];
        __syncthreads();
    }
    if (threadIdx.x == 0) partials[blockIdx.x] = s[0];
}

// ---- Kernel 3b: exclusive scan of partials (single block, nb <= 256) ----
__global__ void __launch_bounds__(256) scan_partials_kernel(
    const int* __restrict__ partials, int* __restrict__ pscan, int nb)
{
    __shared__ int s[256];
    int tid = threadIdx.x;
    s[tid] = (tid < nb) ? partials[tid] : 0;
    for (int off = 1; off < 256; off <<= 1) {
        __syncthreads();
        int x = (tid >= off) ? s[tid - off] : 0;
        __syncthreads();
        s[tid] += x;
    }
    __syncthreads();
    pscan[tid] = (tid == 0) ? 0 : s[tid - 1];
}

// ---- Kernel 3c: block-local exclusive scan + add partial offset ----
__global__ void __launch_bounds__(256) scan_addback_kernel(
    const int* __restrict__ deg, const int* __restrict__ pscan,
    int* __restrict__ offsets, int* __restrict__ cursor,
    int n, int n_edges)
{
    __shared__ int s[256];
    int tid = threadIdx.x;
    int i = blockIdx.x * 256 + tid;
    int v = (i < n) ? deg[i] : 0;
    s[tid] = v;
    for (int off = 1; off < 256; off <<= 1) {
        __syncthreads();
        int x = (tid >= off) ? s[tid - off] : 0;
        __syncthreads();
        s[tid] += x;
    }
    __syncthreads();
    if (i < n) {
        int excl = pscan[blockIdx.x] + s[tid] - v;
        offsets[i] = excl;
        cursor[i]  = excl;
    }
    if (blockIdx.x == 0 && tid == 0) offsets[n] = n_edges;
}

// ---- Kernel 4 (ef_s path): permute src AND edge features ----
__global__ void __launch_bounds__(256) permute_ef_kernel(
    const int* __restrict__ src, const int* __restrict__ dst,
    const float4* __restrict__ ef4, int* __restrict__ cursor,
    int* __restrict__ src_s, float4* __restrict__ efs4, int n_edges)
{
    int e = blockIdx.x * 256 + threadIdx.x;
    if (e >= n_edges) return;
    int pos = atomicAdd(&cursor[dst[e]], 1);
    src_s[pos] = src[e];
    float4 a = ef4[2l * e], c = ef4[2l * e + 1];
    efs4[2l * pos] = a;
    efs4[2l * pos + 1] = c;
}

// ---- Kernel 4' (perm fallback): permute src + edge index ----
__global__ void __launch_bounds__(256) permute_kernel(
    const int* __restrict__ src, const int* __restrict__ dst,
    int* __restrict__ cursor, int* __restrict__ src_s, int* __restrict__ perm,
    int n_edges)
{
    int e = blockIdx.x * 256 + threadIdx.x;
    if (e >= n_edges) return;
    int pos = atomicAdd(&cursor[dst[e]], 1);
    src_s[pos] = src[e];
    perm[pos] = e;
}

// ---- Kernel 5 (ef_s path): aggregation, streaming ef reads ----
__global__ void __launch_bounds__(256) aggregate_stream_kernel(
    const float* __restrict__ t, const float4* __restrict__ efs4,
    const int* __restrict__ src_s, const int* __restrict__ offsets,
    const float* __restrict__ b, float* __restrict__ out, int n_nodes)
{
    int node = (blockIdx.x * 256 + threadIdx.x) >> 6;
    int o = threadIdx.x & 63;
    if (node >= n_nodes) return;

    int beg = offsets[node];
    int end = offsets[node + 1];
    float acc[EDGE_DIM];
    #pragma unroll
    for (int k = 0; k < EDGE_DIM; k++) acc[k] = 0.f;

    int j = beg;
    for (; j + 3 < end; j += 4) {
        int s0 = src_s[j],     s1 = src_s[j + 1];
        int s2 = src_s[j + 2], s3 = src_s[j + 3];
        float tv0 = t[(long)s0 * FEATS + o];
        float tv1 = t[(long)s1 * FEATS + o];
        float tv2 = t[(long)s2 * FEATS + o];
        float tv3 = t[(long)s3 * FEATS + o];
        float4 a0 = efs4[2l * j],     a1 = efs4[2l * j + 1];
        float4 b0 = efs4[2l * j + 2], b1 = efs4[2l * j + 3];
        float4 c0 = efs4[2l * j + 4], c1 = efs4[2l * j + 5];
        float4 d0 = efs4[2l * j + 6], d1 = efs4[2l * j + 7];
        acc[0] += a0.x * tv0 + b0.x * tv1 + c0.x * tv2 + d0.x * tv3;
        acc[1] += a0.y * tv0 + b0.y * tv1 + c0.y * tv2 + d0.y * tv3;
        acc[2] += a0.z * tv0 + b0.z * tv1 + c0.z * tv2 + d0.z * tv3;
        acc[3] += a0.w * tv0 + b0.w * tv1 + c0.w * tv2 + d0.w * tv3;
        acc[4] += a1.x * tv0 + b1.x * tv1 + c1.x * tv2 + d1.x * tv3;
        acc[5] += a1.y * tv0 + b1.y * tv1 + c1.y * tv2 + d1.y * tv3;
        acc[6] += a1.z * tv0 + b1.z * tv1 + c1.z * tv2 + d1.z * tv3;
        acc[7] += a1.w * tv0 + b1.w * tv1 + c1.w * tv2 + d1.w * tv3;
    }
    for (; j < end; j++) {
        int s0 = src_s[j];
        float tv0 = t[(long)s0 * FEATS + o];
        float4 a0 = efs4[2l * j], a1 = efs4[2l * j + 1];
        acc[0] += a0.x * tv0; acc[1] += a0.y * tv0;
        acc[2] += a0.z * tv0; acc[3] += a0.w * tv0;
        acc[4] += a1.x * tv0; acc[5] += a1.y * tv0;
        acc[6] += a1.z * tv0; acc[7] += a1.w * tv0;
    }

    float bo = b[o];
    float* op = out + (long)node * (EDGE_DIM * FEATS) + o;
    #pragma unroll
    for (int k = 0; k < EDGE_DIM; k++)
        __builtin_nontemporal_store(acc[k] + bo, op + k * FEATS);
}

// ---- Kernel 5' (perm fallback): aggregation, ef via perm ----
__global__ void __launch_bounds__(256) aggregate_kernel(
    const float* __restrict__ t, const float* __restrict__ ef,
    const int* __restrict__ src_s, const int* __restrict__ perm,
    const int* __restrict__ offsets, const float* __restrict__ b,
    float* __restrict__ out, int n_nodes)
{
    int node = (blockIdx.x * 256 + threadIdx.x) >> 6;
    int o = threadIdx.x & 63;
    if (node >= n_nodes) return;

    int beg = offsets[node];
    int end = offsets[node + 1];
    float acc[EDGE_DIM];
    #pragma unroll
    for (int k = 0; k < EDGE_DIM; k++) acc[k] = 0.f;

    int j = beg;
    for (; j + 1 < end; j += 2) {
        int e0 = perm[j], e1 = perm[j + 1];
        int s0 = src_s[j], s1 = src_s[j + 1];
        float tv0 = t[(long)s0 * FEATS + o];
        float tv1 = t[(long)s1 * FEATS + o];
        const float4* p0 = (const float4*)(ef + (long)e0 * EDGE_DIM);
        const float4* p1 = (const float4*)(ef + (long)e1 * EDGE_DIM);
        float4 a0 = p0[0], a1 = p0[1];
        float4 c0 = p1[0], c1 = p1[1];
        acc[0] += a0.x * tv0 + c0.x * tv1;
        acc[1] += a0.y * tv0 + c0.y * tv1;
        acc[2] += a0.z * tv0 + c0.z * tv1;
        acc[3] += a0.w * tv0 + c0.w * tv1;
        acc[4] += a1.x * tv0 + c1.x * tv1;
        acc[5] += a1.y * tv0 + c1.y * tv1;
        acc[6] += a1.z * tv0 + c1.z * tv1;
        acc[7] += a1.w * tv0 + c1.w * tv1;
    }
    if (j < end) {
        int e0 = perm[j];
        int s0 = src_s[j];
        float tv0 = t[(long)s0 * FEATS + o];
        const float4* p0 = (const float4*)(ef + (long)e0 * EDGE_DIM);
        float4 a0 = p0[0], a1 = p0[1];
        acc[0] += a0.x * tv0; acc[1] += a0.y * tv0;
        acc[2] += a0.z * tv0; acc[3] += a0.w * tv0;
        acc[4] += a1.x * tv0; acc[5] += a1.y * tv0;
        acc[6] += a1.z * tv0; acc[7] += a1.w * tv0;
    }

    float bo = b[o];
    float* op = out + (long)node * (EDGE_DIM * FEATS) + o;
    #pragma unroll
    for (int k = 0; k < EDGE_DIM; k++)
        __builtin_nontemporal_store(acc[k] + bo, op + k * FEATS);
}

extern "C" void kernel_launch(void* const* d_in, const int* in_sizes, int n_in,
                              void* d_out, int out_size, void* d_ws, size_t ws_size,
                              hipStream_t stream) {
    const float* node_feat = (const float*)d_in[0];
    const float* edge_feat = (const float*)d_in[1];
    const float* W         = (const float*)d_in[2];
    const float* b         = (const float*)d_in[3];
    const int*   src       = (const int*)d_in[4];
    const int*   dst       = (const int*)d_in[5];
    float* out = (float*)d_out;

    const int n_nodes = in_sizes[0] / FEATS;
    const int n_edges = in_sizes[4];
    const int nb_nodes = (n_nodes + 255) / 256;
    const int nb_edges = (n_edges + 255) / 256;

    // workspace layout (4B units)
    int* w = (int*)d_ws;
    float* t      = (float*)w;                          // N*64
    int* deg      = w + (long)n_nodes * FEATS;          // N
    int* offsets  = deg + n_nodes;                      // N+1
    int* cursor   = offsets + n_nodes + 1;              // N
    int* partials = cursor + n_nodes;                   // 256
    int* pscan    = partials + 256;                     // 256
    int* src_s    = pscan + 256;                        // E
    int* tail     = src_s + n_edges;                    // E (perm) or 8E (ef_s)

    // pick path by available workspace (constant across calls -> capture-safe)
    const size_t need_efs = ((size_t)(tail - w) + (size_t)n_edges * EDGE_DIM) * 4;
    const bool use_efs = (ws_size >= need_efs) &&
                         ((((uintptr_t)edge_feat) & 15) == 0) &&
                         ((((uintptr_t)tail) & 15) == 0);

    transform_kernel<<<(n_nodes + 3) / 4, 256, 0, stream>>>(node_feat, W, t, deg, n_nodes);
    hist_kernel<<<(n_edges + 1023) / 1024, 256, 0, stream>>>(dst, deg, n_edges);
    partials_kernel<<<nb_nodes, 256, 0, stream>>>(deg, partials, n_nodes);
    scan_partials_kernel<<<1, 256, 0, stream>>>(partials, pscan, nb_nodes);
    scan_addback_kernel<<<nb_nodes, 256, 0, stream>>>(deg, pscan, offsets, cursor,
                                                      n_nodes, n_edges);

    const long total_ag = (long)n_nodes * 64;
    if (use_efs) {
        permute_ef_kernel<<<nb_edges, 256, 0, stream>>>(
            src, dst, (const float4*)edge_feat, cursor, src_s, (float4*)tail, n_edges);
        aggregate_stream_kernel<<<(int)((total_ag + 255) / 256), 256, 0, stream>>>(
            t, (const float4*)tail, src_s, offsets, b, out, n_nodes);
    } else {
        permute_kernel<<<nb_edges, 256, 0, stream>>>(src, dst, cursor, src_s, tail, n_edges);
        aggregate_kernel<<<(int)((total_ag + 255) / 256), 256, 0, stream>>>(
            t, edge_feat, src_s, tail, offsets, b, out, n_nodes);
    }
}